// Round 8
// baseline (251.782 us; speedup 1.0000x reference)
//
#include <hip/hip_runtime.h>
#include <hip/hip_fp16.h>

// GCN 2-layer, bf16-MFMA GEMM + CSR atomic-free aggregation.
// h1 = relu(Anorm @ (emb[x] @ W1) + b1); out = relu(Anorm @ (h1 @ W2) + b2)
// Anorm = D^-1/2 (A+I) D^-1/2.
// (emb[x]) @ W1 == (emb @ W1)[x]: layer-1 GEMM runs over the 50k-row vocab table.
// Per-edge payload ew[p] = int2(src, fp16(dinv[src])<<16 | x[src]) — ONE 8B scatter
// per edge (line-touch write-amp shrinks as CSR row segments get denser).
//   layer1: out_i = relu(di*(sum_e dinv_e * embW1[x_e] + di*embW1[x_i]) + b1)
//   layer2: rows pre-scaled by dinv in GEMM epilogue (vs2); edge loop adds vs2[src_e].
// Aggregates are dual-row per thread (rows g and g+half) with a lockstep 2+2-edge
// main loop: 2 independent latency chains per thread, 8 gathers in flight.

#define NDIM 128
#define PAD_K 136  // LDS k-stride for B^T (+8 elems = 16B pad)
#define SCAN_IPT 4
#define SCAN_BLK 256
#define SCAN_IPB (SCAN_BLK * SCAN_IPT)

typedef __bf16 bf16x8 __attribute__((ext_vector_type(8)));
typedef float f32x4 __attribute__((ext_vector_type(4)));

__device__ __forceinline__ float bf2f(unsigned short u) {
    union { unsigned int i; float f; } c;
    c.i = (unsigned int)u << 16;
    return c.f;
}
__device__ __forceinline__ unsigned short f2bf(float f) {
    __bf16 b = (__bf16)f;
    return __builtin_bit_cast(unsigned short, b);
}
__device__ __forceinline__ unsigned short f2h(float f) {
    __half h = __float2half_rn(f);
    return __builtin_bit_cast(unsigned short, h);
}
__device__ __forceinline__ float h2f(unsigned short u) {
    return __half2float(__builtin_bit_cast(__half, u));
}
__device__ __forceinline__ void unpack8(uint4 q, float* f) {
    f[0] = bf2f((unsigned short)(q.x & 0xffff));
    f[1] = bf2f((unsigned short)(q.x >> 16));
    f[2] = bf2f((unsigned short)(q.y & 0xffff));
    f[3] = bf2f((unsigned short)(q.y >> 16));
    f[4] = bf2f((unsigned short)(q.z & 0xffff));
    f[5] = bf2f((unsigned short)(q.z >> 16));
    f[6] = bf2f((unsigned short)(q.w & 0xffff));
    f[7] = bf2f((unsigned short)(q.w >> 16));
}

// ---------------- CSR build ----------------
__global__ void degree_count(const int* __restrict__ dst, int* __restrict__ cnt, int E) {
    const int stride = gridDim.x * blockDim.x;
    int e = blockIdx.x * blockDim.x + threadIdx.x;
#pragma unroll
    for (int k = 0; k < 4; ++k) {
        int ee = e + k * stride;
        if (ee < E) atomicAdd(&cnt[dst[ee]], 1);
    }
}

__global__ void scan_blocks(const int* __restrict__ in, int* __restrict__ out,
                            int* __restrict__ bsums, int n) {
    __shared__ int lds[SCAN_BLK];
    const int t = threadIdx.x;
    const int base = blockIdx.x * SCAN_IPB + t * SCAN_IPT;
    int v[SCAN_IPT];
    int s = 0;
#pragma unroll
    for (int k = 0; k < SCAN_IPT; ++k) { v[k] = (base + k < n) ? in[base + k] : 0; s += v[k]; }
    lds[t] = s;
    __syncthreads();
    for (int off = 1; off < SCAN_BLK; off <<= 1) {
        int x = (t >= off) ? lds[t - off] : 0;
        __syncthreads();
        lds[t] += x;
        __syncthreads();
    }
    if (t == SCAN_BLK - 1) bsums[blockIdx.x] = lds[t];
    int run = (t == 0) ? 0 : lds[t - 1];
#pragma unroll
    for (int k = 0; k < SCAN_IPT; ++k) {
        if (base + k < n) out[base + k] = run;
        run += v[k];
    }
}

__global__ void scan_partials(int* __restrict__ bsums, int nb) {
    __shared__ int lds[128];
    const int t = threadIdx.x;
    lds[t] = (t < nb) ? bsums[t] : 0;
    __syncthreads();
    for (int off = 1; off < 128; off <<= 1) {
        int x = (t >= off) ? lds[t - off] : 0;
        __syncthreads();
        lds[t] += x;
        __syncthreads();
    }
    if (t < nb) bsums[t] = (t == 0) ? 0 : lds[t - 1];
}

// blocks [0, nblkA): rp[i]+=bsums, dinv=rsqrt(cnt+1).  blocks [nblkA, ...): W^T bf16 convert.
__global__ void add_offsets_dinv_wt(int* __restrict__ rp, const int* __restrict__ bsums,
                                    const int* __restrict__ cnt, float* __restrict__ dinv, int n,
                                    int nblkA,
                                    const float* __restrict__ W1, const float* __restrict__ W2,
                                    unsigned short* __restrict__ WT1,
                                    unsigned short* __restrict__ WT2) {
    if ((int)blockIdx.x < nblkA) {
        int i = blockIdx.x * blockDim.x + threadIdx.x;
        if (i < n) {
            rp[i] += bsums[i / SCAN_IPB];
            dinv[i] = rsqrtf((float)cnt[i] + 1.0f);  // +1 self-loop
        }
    } else {
        int c = (blockIdx.x - nblkA) * blockDim.x + threadIdx.x;  // 0..32767
        int cc = c & 16383;
        int j = cc >> 7, k = cc & 127;
        if (c < 16384) WT1[cc] = f2bf(W1[k * 128 + j]);
        else if (c < 32768) WT2[cc] = f2bf(W2[k * 128 + j]);
    }
}

// Increments rp[d] in place: afterwards rp[i] == inclusive scan, so row i's edge
// range is [i==0 ? 0 : rp[i-1], rp[i]).  One 8B scatter per edge; 4 edges/thread.
__global__ void fill_edges(const int* __restrict__ src, const int* __restrict__ dst,
                           int* __restrict__ rp, const int* __restrict__ x,
                           const float* __restrict__ dinv, int2* __restrict__ ew, int E) {
    const int stride = gridDim.x * blockDim.x;
    const int e0 = blockIdx.x * blockDim.x + threadIdx.x;
    int s[4], d[4];
#pragma unroll
    for (int k = 0; k < 4; ++k) {
        int ee = e0 + k * stride;
        if (ee < E) { s[k] = src[ee]; d[k] = dst[ee]; } else { s[k] = -1; }
    }
    int xs[4];
    float ds[4];
#pragma unroll
    for (int k = 0; k < 4; ++k) {
        if (s[k] >= 0) { xs[k] = x[s[k]]; ds[k] = dinv[s[k]]; }
    }
#pragma unroll
    for (int k = 0; k < 4; ++k) {
        if (s[k] >= 0) {
            int p = atomicAdd(&rp[d[k]], 1);
            ew[p] = make_int2(s[k], (int)(((unsigned)f2h(ds[k]) << 16) | (unsigned)xs[k]));
        }
    }
}

// ---------------- bf16 MFMA GEMM: outb[r][:] = (dinv[r]?) * (A[r][:] @ W) ----------------
// MODE 0: A rows fp32 (sequential, convert inline).  MODE 1: A rows bf16.
// Block: 256 threads (4 waves), tile 64 rows x 128 cols; wave w rows [16w,16w+16).
// A fragments read DIRECTLY from global; only B^T staged in LDS (34 KB -> 4 blocks/CU).
// A-frag A[m=lane&15][k=quad*8+j]; B-frag B[k][n=lane&15] (B^T staged [n][k]);
// C/D: col=lane&15, row=quad*4+reg.
template <int MODE, bool SCALE>
__global__ __launch_bounds__(256, 4)
void gemm_mfma(const void* __restrict__ Asrc, const unsigned short* __restrict__ WTb,
               const float* __restrict__ dinv, unsigned short* __restrict__ outb, int n) {
    __shared__ __bf16 sBT[128 * PAD_K];
    const int tid = threadIdx.x;
    const int rbase = blockIdx.x * 64;

    {
        const uint4* bsrc = (const uint4*)WTb;
#pragma unroll
        for (int i = 0; i < 8; ++i) {
            int c = tid + i * 256;          // 2048 x 16B
            int j = c >> 4, u = c & 15;
            *(uint4*)&sBT[j * PAD_K + u * 8] = bsrc[c];
        }
    }
    __syncthreads();

    const int wave = tid >> 6, lane = tid & 63;
    const int quad = lane >> 4, lrow = lane & 15;
    int arow = rbase + wave * 16 + lrow;
    if (arow >= n) arow = n - 1;  // clamp; guarded at store

    f32x4 acc[8];
#pragma unroll
    for (int nt = 0; nt < 8; ++nt) acc[nt] = (f32x4)0.0f;

#pragma unroll
    for (int ks = 0; ks < 4; ++ks) {
        const int kb = ks * 32 + quad * 8;
        bf16x8 a;
        if (MODE == 0) {
            const float4* A4 = (const float4*)Asrc;
            float4 v0 = A4[(size_t)arow * 32 + (kb >> 2)];
            float4 v1 = A4[(size_t)arow * 32 + (kb >> 2) + 1];
            a = (bf16x8){(__bf16)v0.x, (__bf16)v0.y, (__bf16)v0.z, (__bf16)v0.w,
                         (__bf16)v1.x, (__bf16)v1.y, (__bf16)v1.z, (__bf16)v1.w};
        } else {
            a = *(const bf16x8*)((const unsigned short*)Asrc + (size_t)arow * 128 + kb);
        }
#pragma unroll
        for (int nt = 0; nt < 8; ++nt) {
            bf16x8 b = *(const bf16x8*)&sBT[(nt * 16 + lrow) * PAD_K + kb];
            acc[nt] = __builtin_amdgcn_mfma_f32_16x16x32_bf16(a, b, acc[nt], 0, 0, 0);
        }
    }

    // store: row = rbase + 16*wave + 4*quad + r, col = 16*nt + lrow
#pragma unroll
    for (int r = 0; r < 4; ++r) {
        int grow = rbase + wave * 16 + quad * 4 + r;
        if (grow < n) {
            float dsc = SCALE ? dinv[grow] : 1.0f;
            unsigned short* orow = outb + (size_t)grow * NDIM + lrow;
#pragma unroll
            for (int nt = 0; nt < 8; ++nt)
                orow[nt * 16] = f2bf(SCALE ? dsc * acc[nt][r] : acc[nt][r]);
        }
    }
}

// ---------------- layer-1 aggregation: dual-row threads, gathers from embW1 table ----
// ew.y: low16 = x[src], high16 = fp16(dinv[src]).
__global__ void aggregate1(const unsigned short* __restrict__ tab, const int* __restrict__ x,
                           const int* __restrict__ rp, const int2* __restrict__ ew,
                           const float* __restrict__ dinv, const float* __restrict__ bias,
                           unsigned short* __restrict__ outb, int n, int half) {
    int t = blockIdx.x * blockDim.x + threadIdx.x;
    int g = t >> 4, u = t & 15;
    if (g >= half) return;
    const uint4* tab4 = (const uint4*)tab;  // row = 16 x uint4
    const int i0 = g, i1 = g + half;
    const bool has1 = (i1 < n);
    float di0 = dinv[i0];
    float di1 = has1 ? dinv[i1] : 0.0f;
    float acc0[8], acc1[8];
    {
        float f[8];
        unpack8(tab4[(size_t)x[i0] * 16 + u], f);
#pragma unroll
        for (int k = 0; k < 8; ++k) acc0[k] = di0 * f[k];
    }
    if (has1) {
        float f[8];
        unpack8(tab4[(size_t)x[i1] * 16 + u], f);
#pragma unroll
        for (int k = 0; k < 8; ++k) acc1[k] = di1 * f[k];
    }
    int j0 = (i0 == 0) ? 0 : rp[i0 - 1];
    const int e0 = rp[i0];
    int j1 = has1 ? rp[i1 - 1] : 0;
    const int e1 = has1 ? rp[i1] : 0;

    // lockstep phase: 2 edges per row per iteration -> 4 gathers + 4 ew loads in flight
    while (j0 + 2 <= e0 && j1 + 2 <= e1) {
        int2 a0 = ew[j0], a1 = ew[j0 + 1], c0 = ew[j1], c1 = ew[j1 + 1];
        uint4 qa0 = tab4[(size_t)(a0.y & 0xffff) * 16 + u];
        uint4 qa1 = tab4[(size_t)(a1.y & 0xffff) * 16 + u];
        uint4 qc0 = tab4[(size_t)(c0.y & 0xffff) * 16 + u];
        uint4 qc1 = tab4[(size_t)(c1.y & 0xffff) * 16 + u];
        float fa0[8], fa1[8], fc0[8], fc1[8];
        unpack8(qa0, fa0); unpack8(qa1, fa1); unpack8(qc0, fc0); unpack8(qc1, fc1);
        float na0 = h2f((unsigned short)((unsigned)a0.y >> 16));
        float na1 = h2f((unsigned short)((unsigned)a1.y >> 16));
        float nc0 = h2f((unsigned short)((unsigned)c0.y >> 16));
        float nc1 = h2f((unsigned short)((unsigned)c1.y >> 16));
#pragma unroll
        for (int k = 0; k < 8; ++k) {
            acc0[k] += fmaf(na0, fa0[k], na1 * fa1[k]);
            acc1[k] += fmaf(nc0, fc0[k], nc1 * fc1[k]);
        }
        j0 += 2; j1 += 2;
    }
    // drain row 0
    for (; j0 + 2 <= e0; j0 += 2) {
        int2 a0 = ew[j0], a1 = ew[j0 + 1];
        uint4 qa0 = tab4[(size_t)(a0.y & 0xffff) * 16 + u];
        uint4 qa1 = tab4[(size_t)(a1.y & 0xffff) * 16 + u];
        float fa0[8], fa1[8];
        unpack8(qa0, fa0); unpack8(qa1, fa1);
        float na0 = h2f((unsigned short)((unsigned)a0.y >> 16));
        float na1 = h2f((unsigned short)((unsigned)a1.y >> 16));
#pragma unroll
        for (int k = 0; k < 8; ++k) acc0[k] += fmaf(na0, fa0[k], na1 * fa1[k]);
    }
    if (j0 < e0) {
        int2 a = ew[j0];
        uint4 q = tab4[(size_t)(a.y & 0xffff) * 16 + u];
        float f[8];
        unpack8(q, f);
        float nm = h2f((unsigned short)((unsigned)a.y >> 16));
#pragma unroll
        for (int k = 0; k < 8; ++k) acc0[k] = fmaf(nm, f[k], acc0[k]);
    }
    // drain row 1
    for (; j1 + 2 <= e1; j1 += 2) {
        int2 c0 = ew[j1], c1 = ew[j1 + 1];
        uint4 qc0 = tab4[(size_t)(c0.y & 0xffff) * 16 + u];
        uint4 qc1 = tab4[(size_t)(c1.y & 0xffff) * 16 + u];
        float fc0[8], fc1[8];
        unpack8(qc0, fc0); unpack8(qc1, fc1);
        float nc0 = h2f((unsigned short)((unsigned)c0.y >> 16));
        float nc1 = h2f((unsigned short)((unsigned)c1.y >> 16));
#pragma unroll
        for (int k = 0; k < 8; ++k) acc1[k] += fmaf(nc0, fc0[k], nc1 * fc1[k]);
    }
    if (j1 < e1) {
        int2 c = ew[j1];
        uint4 q = tab4[(size_t)(c.y & 0xffff) * 16 + u];
        float f[8];
        unpack8(q, f);
        float nm = h2f((unsigned short)((unsigned)c.y >> 16));
#pragma unroll
        for (int k = 0; k < 8; ++k) acc1[k] = fmaf(nm, f[k], acc1[k]);
    }

    const float4 b0 = ((const float4*)bias)[u * 2];
    const float4 b1 = ((const float4*)bias)[u * 2 + 1];
    {
        float r[8];
        r[0] = fmaxf(fmaf(di0, acc0[0], b0.x), 0.0f);
        r[1] = fmaxf(fmaf(di0, acc0[1], b0.y), 0.0f);
        r[2] = fmaxf(fmaf(di0, acc0[2], b0.z), 0.0f);
        r[3] = fmaxf(fmaf(di0, acc0[3], b0.w), 0.0f);
        r[4] = fmaxf(fmaf(di0, acc0[4], b1.x), 0.0f);
        r[5] = fmaxf(fmaf(di0, acc0[5], b1.y), 0.0f);
        r[6] = fmaxf(fmaf(di0, acc0[6], b1.z), 0.0f);
        r[7] = fmaxf(fmaf(di0, acc0[7], b1.w), 0.0f);
        uint4 o;
        o.x = (unsigned)f2bf(r[0]) | ((unsigned)f2bf(r[1]) << 16);
        o.y = (unsigned)f2bf(r[2]) | ((unsigned)f2bf(r[3]) << 16);
        o.z = (unsigned)f2bf(r[4]) | ((unsigned)f2bf(r[5]) << 16);
        o.w = (unsigned)f2bf(r[6]) | ((unsigned)f2bf(r[7]) << 16);
        ((uint4*)outb)[(size_t)i0 * 16 + u] = o;
    }
    if (has1) {
        float r[8];
        r[0] = fmaxf(fmaf(di1, acc1[0], b0.x), 0.0f);
        r[1] = fmaxf(fmaf(di1, acc1[1], b0.y), 0.0f);
        r[2] = fmaxf(fmaf(di1, acc1[2], b0.z), 0.0f);
        r[3] = fmaxf(fmaf(di1, acc1[3], b0.w), 0.0f);
        r[4] = fmaxf(fmaf(di1, acc1[4], b1.x), 0.0f);
        r[5] = fmaxf(fmaf(di1, acc1[5], b1.y), 0.0f);
        r[6] = fmaxf(fmaf(di1, acc1[6], b1.z), 0.0f);
        r[7] = fmaxf(fmaf(di1, acc1[7], b1.w), 0.0f);
        uint4 o;
        o.x = (unsigned)f2bf(r[0]) | ((unsigned)f2bf(r[1]) << 16);
        o.y = (unsigned)f2bf(r[2]) | ((unsigned)f2bf(r[3]) << 16);
        o.z = (unsigned)f2bf(r[4]) | ((unsigned)f2bf(r[5]) << 16);
        o.w = (unsigned)f2bf(r[6]) | ((unsigned)f2bf(r[7]) << 16);
        ((uint4*)outb)[(size_t)i1 * 16 + u] = o;
    }
}

// ---------------- layer-2 aggregation: dual-row, vs2 rows pre-scaled, fp32 output ----
__global__ void aggregate2(const unsigned short* __restrict__ vs, const int* __restrict__ rp,
                           const int2* __restrict__ ew, const float* __restrict__ dinv,
                           const float* __restrict__ bias, float* __restrict__ out,
                           int n, int half) {
    int t = blockIdx.x * blockDim.x + threadIdx.x;
    int g = t >> 4, u = t & 15;
    if (g >= half) return;
    const uint4* vs4 = (const uint4*)vs;
    const int i0 = g, i1 = g + half;
    const bool has1 = (i1 < n);
    float acc0[8], acc1[8];
    unpack8(vs4[(size_t)i0 * 16 + u], acc0);  // self term (already di-scaled)
    if (has1) unpack8(vs4[(size_t)i1 * 16 + u], acc1);
    int j0 = (i0 == 0) ? 0 : rp[i0 - 1];
    const int e0 = rp[i0];
    int j1 = has1 ? rp[i1 - 1] : 0;
    const int e1 = has1 ? rp[i1] : 0;

    while (j0 + 2 <= e0 && j1 + 2 <= e1) {
        int s00 = ew[j0].x, s01 = ew[j0 + 1].x, s10 = ew[j1].x, s11 = ew[j1 + 1].x;
        uint4 q00 = vs4[(size_t)s00 * 16 + u];
        uint4 q01 = vs4[(size_t)s01 * 16 + u];
        uint4 q10 = vs4[(size_t)s10 * 16 + u];
        uint4 q11 = vs4[(size_t)s11 * 16 + u];
        float f00[8], f01[8], f10[8], f11[8];
        unpack8(q00, f00); unpack8(q01, f01); unpack8(q10, f10); unpack8(q11, f11);
#pragma unroll
        for (int k = 0; k < 8; ++k) {
            acc0[k] += f00[k] + f01[k];
            acc1[k] += f10[k] + f11[k];
        }
        j0 += 2; j1 += 2;
    }
    for (; j0 + 2 <= e0; j0 += 2) {
        int s00 = ew[j0].x, s01 = ew[j0 + 1].x;
        uint4 q00 = vs4[(size_t)s00 * 16 + u];
        uint4 q01 = vs4[(size_t)s01 * 16 + u];
        float f00[8], f01[8];
        unpack8(q00, f00); unpack8(q01, f01);
#pragma unroll
        for (int k = 0; k < 8; ++k) acc0[k] += f00[k] + f01[k];
    }
    if (j0 < e0) {
        uint4 q = vs4[(size_t)ew[j0].x * 16 + u];
        float f[8];
        unpack8(q, f);
#pragma unroll
        for (int k = 0; k < 8; ++k) acc0[k] += f[k];
    }
    for (; j1 + 2 <= e1; j1 += 2) {
        int s10 = ew[j1].x, s11 = ew[j1 + 1].x;
        uint4 q10 = vs4[(size_t)s10 * 16 + u];
        uint4 q11 = vs4[(size_t)s11 * 16 + u];
        float f10[8], f11[8];
        unpack8(q10, f10); unpack8(q11, f11);
#pragma unroll
        for (int k = 0; k < 8; ++k) acc1[k] += f10[k] + f11[k];
    }
    if (j1 < e1) {
        uint4 q = vs4[(size_t)ew[j1].x * 16 + u];
        float f[8];
        unpack8(q, f);
#pragma unroll
        for (int k = 0; k < 8; ++k) acc1[k] += f[k];
    }

    const float4 b0 = ((const float4*)bias)[u * 2];
    const float4 b1 = ((const float4*)bias)[u * 2 + 1];
    {
        float di = dinv[i0];
        float4 r0, r1;
        r0.x = fmaxf(fmaf(di, acc0[0], b0.x), 0.0f);
        r0.y = fmaxf(fmaf(di, acc0[1], b0.y), 0.0f);
        r0.z = fmaxf(fmaf(di, acc0[2], b0.z), 0.0f);
        r0.w = fmaxf(fmaf(di, acc0[3], b0.w), 0.0f);
        r1.x = fmaxf(fmaf(di, acc0[4], b1.x), 0.0f);
        r1.y = fmaxf(fmaf(di, acc0[5], b1.y), 0.0f);
        r1.z = fmaxf(fmaf(di, acc0[6], b1.z), 0.0f);
        r1.w = fmaxf(fmaf(di, acc0[7], b1.w), 0.0f);
        ((float4*)out)[(size_t)i0 * 32 + u * 2] = r0;
        ((float4*)out)[(size_t)i0 * 32 + u * 2 + 1] = r1;
    }
    if (has1) {
        float di = dinv[i1];
        float4 r0, r1;
        r0.x = fmaxf(fmaf(di, acc1[0], b0.x), 0.0f);
        r0.y = fmaxf(fmaf(di, acc1[1], b0.y), 0.0f);
        r0.z = fmaxf(fmaf(di, acc1[2], b0.z), 0.0f);
        r0.w = fmaxf(fmaf(di, acc1[3], b0.w), 0.0f);
        r1.x = fmaxf(fmaf(di, acc1[4], b1.x), 0.0f);
        r1.y = fmaxf(fmaf(di, acc1[5], b1.y), 0.0f);
        r1.z = fmaxf(fmaf(di, acc1[6], b1.z), 0.0f);
        r1.w = fmaxf(fmaf(di, acc1[7], b1.w), 0.0f);
        ((float4*)out)[(size_t)i1 * 32 + u * 2] = r0;
        ((float4*)out)[(size_t)i1 * 32 + u * 2 + 1] = r1;
    }
}

extern "C" void kernel_launch(void* const* d_in, const int* in_sizes, int n_in,
                              void* d_out, int out_size, void* d_ws, size_t ws_size,
                              hipStream_t stream) {
    const int* x = (const int*)d_in[0];
    const int* edge_index = (const int*)d_in[1];
    const float* emb = (const float*)d_in[2];
    const float* W1 = (const float*)d_in[3];
    const float* b1 = (const float*)d_in[4];
    const float* W2 = (const float*)d_in[5];
    const float* b2 = (const float*)d_in[6];
    float* out = (float*)d_out;

    const int N = in_sizes[0];
    const int E = in_sizes[1] / 2;
    const int V = in_sizes[2] / NDIM;  // vocab rows
    const int* src = edge_index;
    const int* dst = edge_index + E;

    char* p = (char*)d_ws;
    auto alloc = [&](size_t bytes) {
        char* q = p;
        p += (bytes + 511) & ~(size_t)511;
        return q;
    };
    int* cnt = (int*)alloc((size_t)N * sizeof(int));
    int* rp = (int*)alloc((size_t)N * sizeof(int));
    float* dinv = (float*)alloc((size_t)N * sizeof(float));
    int* bsums = (int*)alloc(128 * sizeof(int));
    int2* ew = (int2*)alloc((size_t)E * sizeof(int2));
    unsigned short* WT1 = (unsigned short*)alloc(16384 * sizeof(unsigned short));
    unsigned short* WT2 = (unsigned short*)alloc(16384 * sizeof(unsigned short));
    unsigned short* embW1 = (unsigned short*)alloc((size_t)V * NDIM * sizeof(unsigned short));
    unsigned short* h1b = (unsigned short*)alloc((size_t)N * NDIM * sizeof(unsigned short));
    unsigned short* vs2 = (unsigned short*)alloc((size_t)N * NDIM * sizeof(unsigned short));
    (void)ws_size;

    const int NB = (N + SCAN_IPB - 1) / SCAN_IPB;  // 98 <= 128
    const int nblkA = (N + 255) / 256;
    const int half = (N + 1) / 2;

    // CSR build + dinv (rp becomes inclusive scan after fill_edges)
    hipMemsetAsync(cnt, 0, (size_t)N * sizeof(int), stream);
    degree_count<<<(E / 4 + 255) / 256, 256, 0, stream>>>(dst, cnt, E);
    scan_blocks<<<NB, SCAN_BLK, 0, stream>>>(cnt, rp, bsums, N);
    scan_partials<<<1, 128, 0, stream>>>(bsums, NB);
    add_offsets_dinv_wt<<<nblkA + 128, 256, 0, stream>>>(rp, bsums, cnt, dinv, N, nblkA,
                                                         W1, W2, WT1, WT2);
    fill_edges<<<(E / 4 + 255) / 256, 256, 0, stream>>>(src, dst, rp, x, dinv, ew, E);

    const int agg_blocks = (int)(((size_t)half * 16 + 255) / 256);

    // layer 1: vocab-table GEMM, then fused gather-aggregate
    gemm_mfma<0, false><<<(V + 63) / 64, 256, 0, stream>>>(emb, WT1, nullptr, embW1, V);
    aggregate1<<<agg_blocks, 256, 0, stream>>>(embW1, x, rp, ew, dinv, b1, h1b, N, half);
    // layer 2
    gemm_mfma<1, true><<<(N + 63) / 64, 256, 0, stream>>>(h1b, WT2, dinv, vs2, N);
    aggregate2<<<agg_blocks, 256, 0, stream>>>(vs2, rp, ew, dinv, b2, out, N, half);
}

// Round 9
// 242.142 us; speedup vs baseline: 1.0398x; 1.0398x over previous
//
#include <hip/hip_runtime.h>
#include <hip/hip_fp16.h>

// GCN 2-layer, bf16-MFMA GEMM + CSR atomic-free aggregation.
// h1 = relu(Anorm @ (emb[x] @ W1) + b1); out = relu(Anorm @ (h1 @ W2) + b2)
// Anorm = D^-1/2 (A+I) D^-1/2.
// (emb[x]) @ W1 == (emb @ W1)[x]: layer-1 GEMM runs over the 50k-row vocab table.
// Per-edge payload ew[p] = int2(src, fp16(dinv[src])<<16 | x[src]) — one 8B scatter/edge.
// fill_edges (latency-bound scatter) and the vocab GEMM are INDEPENDENT -> fused into
// one dispatch branching on blockIdx so they overlap (fill was serial-exposed before).
//   layer1: out_i = relu(di*(sum_e dinv_e * embW1[x_e] + di*embW1[x_i]) + b1)
//   layer2: rows pre-scaled by dinv in GEMM epilogue (vs2); edge loop adds vs2[src_e].
// Aggregates: dual-row per thread, lockstep 2+2-edge loop (8 gathers in flight).

#define NDIM 128
#define PAD_K 136  // LDS k-stride for B^T (+8 elems = 16B pad)
#define SCAN_IPT 4
#define SCAN_BLK 256
#define SCAN_IPB (SCAN_BLK * SCAN_IPT)

typedef __bf16 bf16x8 __attribute__((ext_vector_type(8)));
typedef float f32x4 __attribute__((ext_vector_type(4)));

__device__ __forceinline__ float bf2f(unsigned short u) {
    union { unsigned int i; float f; } c;
    c.i = (unsigned int)u << 16;
    return c.f;
}
__device__ __forceinline__ unsigned short f2bf(float f) {
    __bf16 b = (__bf16)f;
    return __builtin_bit_cast(unsigned short, b);
}
__device__ __forceinline__ unsigned short f2h(float f) {
    __half h = __float2half_rn(f);
    return __builtin_bit_cast(unsigned short, h);
}
__device__ __forceinline__ float h2f(unsigned short u) {
    return __half2float(__builtin_bit_cast(__half, u));
}
__device__ __forceinline__ void unpack8(uint4 q, float* f) {
    f[0] = bf2f((unsigned short)(q.x & 0xffff));
    f[1] = bf2f((unsigned short)(q.x >> 16));
    f[2] = bf2f((unsigned short)(q.y & 0xffff));
    f[3] = bf2f((unsigned short)(q.y >> 16));
    f[4] = bf2f((unsigned short)(q.z & 0xffff));
    f[5] = bf2f((unsigned short)(q.z >> 16));
    f[6] = bf2f((unsigned short)(q.w & 0xffff));
    f[7] = bf2f((unsigned short)(q.w >> 16));
}

// ---------------- CSR build ----------------
__global__ void degree_count(const int* __restrict__ dst, int* __restrict__ cnt, int E) {
    const int stride = gridDim.x * blockDim.x;
    int e = blockIdx.x * blockDim.x + threadIdx.x;
#pragma unroll
    for (int k = 0; k < 2; ++k) {
        int ee = e + k * stride;
        if (ee < E) atomicAdd(&cnt[dst[ee]], 1);
    }
}

__global__ void scan_blocks(const int* __restrict__ in, int* __restrict__ out,
                            int* __restrict__ bsums, int n) {
    __shared__ int lds[SCAN_BLK];
    const int t = threadIdx.x;
    const int base = blockIdx.x * SCAN_IPB + t * SCAN_IPT;
    int v[SCAN_IPT];
    int s = 0;
#pragma unroll
    for (int k = 0; k < SCAN_IPT; ++k) { v[k] = (base + k < n) ? in[base + k] : 0; s += v[k]; }
    lds[t] = s;
    __syncthreads();
    for (int off = 1; off < SCAN_BLK; off <<= 1) {
        int x = (t >= off) ? lds[t - off] : 0;
        __syncthreads();
        lds[t] += x;
        __syncthreads();
    }
    if (t == SCAN_BLK - 1) bsums[blockIdx.x] = lds[t];
    int run = (t == 0) ? 0 : lds[t - 1];
#pragma unroll
    for (int k = 0; k < SCAN_IPT; ++k) {
        if (base + k < n) out[base + k] = run;
        run += v[k];
    }
}

__global__ void scan_partials(int* __restrict__ bsums, int nb) {
    __shared__ int lds[128];
    const int t = threadIdx.x;
    lds[t] = (t < nb) ? bsums[t] : 0;
    __syncthreads();
    for (int off = 1; off < 128; off <<= 1) {
        int x = (t >= off) ? lds[t - off] : 0;
        __syncthreads();
        lds[t] += x;
        __syncthreads();
    }
    if (t < nb) bsums[t] = (t == 0) ? 0 : lds[t - 1];
}

// blocks [0, nblkA): rp[i]+=bsums, dinv=rsqrt(cnt+1).  blocks [nblkA, ...): W^T bf16 convert.
__global__ void add_offsets_dinv_wt(int* __restrict__ rp, const int* __restrict__ bsums,
                                    const int* __restrict__ cnt, float* __restrict__ dinv, int n,
                                    int nblkA,
                                    const float* __restrict__ W1, const float* __restrict__ W2,
                                    unsigned short* __restrict__ WT1,
                                    unsigned short* __restrict__ WT2) {
    if ((int)blockIdx.x < nblkA) {
        int i = blockIdx.x * blockDim.x + threadIdx.x;
        if (i < n) {
            rp[i] += bsums[i / SCAN_IPB];
            dinv[i] = rsqrtf((float)cnt[i] + 1.0f);  // +1 self-loop
        }
    } else {
        int c = (blockIdx.x - nblkA) * blockDim.x + threadIdx.x;  // 0..32767
        int cc = c & 16383;
        int j = cc >> 7, k = cc & 127;
        if (c < 16384) WT1[cc] = f2bf(W1[k * 128 + j]);
        else if (c < 32768) WT2[cc] = f2bf(W2[k * 128 + j]);
    }
}

// ---------------- fused: vocab GEMM (blocks [0,gemmBlocks)) + edge fill (rest) ----------
// GEMM: embW1[r][:] = bf16(emb[r][:] @ W1), r in [0,V).  64 rows x 128 cols per block,
// A fragments read directly from global fp32; B^T staged in LDS.
// mfma_f32_16x16x32_bf16: A-frag A[m=lane&15][k=quad*8+j]; B-frag B[k][n=lane&15];
// C/D: col=lane&15, row=quad*4+reg.
// FILL: rp[d] incremented in place (-> inclusive scan); one 8B scatter per edge,
// 2 edges/thread for resident-wave concurrency (round-7 lesson: occupancy >> unroll).
__global__ __launch_bounds__(256, 4)
void gemm1_fill(const float* __restrict__ emb, const unsigned short* __restrict__ WT1,
                unsigned short* __restrict__ embW1, int V, int gemmBlocks,
                const int* __restrict__ src, const int* __restrict__ dst,
                int* __restrict__ rp, const int* __restrict__ x,
                const float* __restrict__ dinv, int2* __restrict__ ew, int E,
                int fillBlocks) {
    __shared__ __bf16 sBT[128 * PAD_K];
    const int tid = threadIdx.x;

    if ((int)blockIdx.x < gemmBlocks) {
        const int rbase = blockIdx.x * 64;
        {
            const uint4* bsrc = (const uint4*)WT1;
#pragma unroll
            for (int i = 0; i < 8; ++i) {
                int c = tid + i * 256;          // 2048 x 16B
                int j = c >> 4, u = c & 15;
                *(uint4*)&sBT[j * PAD_K + u * 8] = bsrc[c];
            }
        }
        __syncthreads();

        const int wave = tid >> 6, lane = tid & 63;
        const int quad = lane >> 4, lrow = lane & 15;
        int arow = rbase + wave * 16 + lrow;
        if (arow >= V) arow = V - 1;  // clamp; guarded at store

        f32x4 acc[8];
#pragma unroll
        for (int nt = 0; nt < 8; ++nt) acc[nt] = (f32x4)0.0f;

#pragma unroll
        for (int ks = 0; ks < 4; ++ks) {
            const int kb = ks * 32 + quad * 8;
            const float4* A4 = (const float4*)emb;
            float4 v0 = A4[(size_t)arow * 32 + (kb >> 2)];
            float4 v1 = A4[(size_t)arow * 32 + (kb >> 2) + 1];
            bf16x8 a = (bf16x8){(__bf16)v0.x, (__bf16)v0.y, (__bf16)v0.z, (__bf16)v0.w,
                                (__bf16)v1.x, (__bf16)v1.y, (__bf16)v1.z, (__bf16)v1.w};
#pragma unroll
            for (int nt = 0; nt < 8; ++nt) {
                bf16x8 b = *(const bf16x8*)&sBT[(nt * 16 + lrow) * PAD_K + kb];
                acc[nt] = __builtin_amdgcn_mfma_f32_16x16x32_bf16(a, b, acc[nt], 0, 0, 0);
            }
        }

#pragma unroll
        for (int r = 0; r < 4; ++r) {
            int grow = rbase + wave * 16 + quad * 4 + r;
            if (grow < V) {
                unsigned short* orow = embW1 + (size_t)grow * NDIM + lrow;
#pragma unroll
                for (int nt = 0; nt < 8; ++nt)
                    orow[nt * 16] = f2bf(acc[nt][r]);
            }
        }
    } else {
        const int bid = blockIdx.x - gemmBlocks;
        const int stride = fillBlocks * 256;
        int e = bid * 256 + tid;
#pragma unroll
        for (int k = 0; k < 2; ++k, e += stride) {
            if (e < E) {
                int d = dst[e], s = src[e];
                int xs = x[s];
                float ds = dinv[s];
                int p = atomicAdd(&rp[d], 1);
                ew[p] = make_int2(s, (int)(((unsigned)f2h(ds) << 16) | (unsigned)xs));
            }
        }
    }
}

// ---------------- layer-2 GEMM: vs2[r][:] = bf16(dinv[r] * (h1b[r][:] @ W2)) ----------
__global__ __launch_bounds__(256, 4)
void gemm_mfma_b(const unsigned short* __restrict__ Asrc, const unsigned short* __restrict__ WTb,
                 const float* __restrict__ dinv, unsigned short* __restrict__ outb, int n) {
    __shared__ __bf16 sBT[128 * PAD_K];
    const int tid = threadIdx.x;
    const int rbase = blockIdx.x * 64;

    {
        const uint4* bsrc = (const uint4*)WTb;
#pragma unroll
        for (int i = 0; i < 8; ++i) {
            int c = tid + i * 256;          // 2048 x 16B
            int j = c >> 4, u = c & 15;
            *(uint4*)&sBT[j * PAD_K + u * 8] = bsrc[c];
        }
    }
    __syncthreads();

    const int wave = tid >> 6, lane = tid & 63;
    const int quad = lane >> 4, lrow = lane & 15;
    int arow = rbase + wave * 16 + lrow;
    if (arow >= n) arow = n - 1;  // clamp; guarded at store

    f32x4 acc[8];
#pragma unroll
    for (int nt = 0; nt < 8; ++nt) acc[nt] = (f32x4)0.0f;

#pragma unroll
    for (int ks = 0; ks < 4; ++ks) {
        const int kb = ks * 32 + quad * 8;
        bf16x8 a = *(const bf16x8*)(Asrc + (size_t)arow * 128 + kb);
#pragma unroll
        for (int nt = 0; nt < 8; ++nt) {
            bf16x8 b = *(const bf16x8*)&sBT[(nt * 16 + lrow) * PAD_K + kb];
            acc[nt] = __builtin_amdgcn_mfma_f32_16x16x32_bf16(a, b, acc[nt], 0, 0, 0);
        }
    }

#pragma unroll
    for (int r = 0; r < 4; ++r) {
        int grow = rbase + wave * 16 + quad * 4 + r;
        if (grow < n) {
            float dsc = dinv[grow];
            unsigned short* orow = outb + (size_t)grow * NDIM + lrow;
#pragma unroll
            for (int nt = 0; nt < 8; ++nt)
                orow[nt * 16] = f2bf(dsc * acc[nt][r]);
        }
    }
}

// ---------------- layer-1 aggregation: dual-row threads, gathers from embW1 table ----
// ew.y: low16 = x[src], high16 = fp16(dinv[src]).
__global__ void aggregate1(const unsigned short* __restrict__ tab, const int* __restrict__ x,
                           const int* __restrict__ rp, const int2* __restrict__ ew,
                           const float* __restrict__ dinv, const float* __restrict__ bias,
                           unsigned short* __restrict__ outb, int n, int half) {
    int t = blockIdx.x * blockDim.x + threadIdx.x;
    int g = t >> 4, u = t & 15;
    if (g >= half) return;
    const uint4* tab4 = (const uint4*)tab;  // row = 16 x uint4
    const int i0 = g, i1 = g + half;
    const bool has1 = (i1 < n);
    float di0 = dinv[i0];
    float di1 = has1 ? dinv[i1] : 0.0f;
    float acc0[8], acc1[8];
    {
        float f[8];
        unpack8(tab4[(size_t)x[i0] * 16 + u], f);
#pragma unroll
        for (int k = 0; k < 8; ++k) acc0[k] = di0 * f[k];
    }
    if (has1) {
        float f[8];
        unpack8(tab4[(size_t)x[i1] * 16 + u], f);
#pragma unroll
        for (int k = 0; k < 8; ++k) acc1[k] = di1 * f[k];
    }
    int j0 = (i0 == 0) ? 0 : rp[i0 - 1];
    const int e0 = rp[i0];
    int j1 = has1 ? rp[i1 - 1] : 0;
    const int e1 = has1 ? rp[i1] : 0;

    // lockstep phase: 2 edges per row per iteration -> 4 gathers + 4 ew loads in flight
    while (j0 + 2 <= e0 && j1 + 2 <= e1) {
        int2 a0 = ew[j0], a1 = ew[j0 + 1], c0 = ew[j1], c1 = ew[j1 + 1];
        uint4 qa0 = tab4[(size_t)(a0.y & 0xffff) * 16 + u];
        uint4 qa1 = tab4[(size_t)(a1.y & 0xffff) * 16 + u];
        uint4 qc0 = tab4[(size_t)(c0.y & 0xffff) * 16 + u];
        uint4 qc1 = tab4[(size_t)(c1.y & 0xffff) * 16 + u];
        float fa0[8], fa1[8], fc0[8], fc1[8];
        unpack8(qa0, fa0); unpack8(qa1, fa1); unpack8(qc0, fc0); unpack8(qc1, fc1);
        float na0 = h2f((unsigned short)((unsigned)a0.y >> 16));
        float na1 = h2f((unsigned short)((unsigned)a1.y >> 16));
        float nc0 = h2f((unsigned short)((unsigned)c0.y >> 16));
        float nc1 = h2f((unsigned short)((unsigned)c1.y >> 16));
#pragma unroll
        for (int k = 0; k < 8; ++k) {
            acc0[k] += fmaf(na0, fa0[k], na1 * fa1[k]);
            acc1[k] += fmaf(nc0, fc0[k], nc1 * fc1[k]);
        }
        j0 += 2; j1 += 2;
    }
    // drain row 0
    for (; j0 + 2 <= e0; j0 += 2) {
        int2 a0 = ew[j0], a1 = ew[j0 + 1];
        uint4 qa0 = tab4[(size_t)(a0.y & 0xffff) * 16 + u];
        uint4 qa1 = tab4[(size_t)(a1.y & 0xffff) * 16 + u];
        float fa0[8], fa1[8];
        unpack8(qa0, fa0); unpack8(qa1, fa1);
        float na0 = h2f((unsigned short)((unsigned)a0.y >> 16));
        float na1 = h2f((unsigned short)((unsigned)a1.y >> 16));
#pragma unroll
        for (int k = 0; k < 8; ++k) acc0[k] += fmaf(na0, fa0[k], na1 * fa1[k]);
    }
    if (j0 < e0) {
        int2 a = ew[j0];
        uint4 q = tab4[(size_t)(a.y & 0xffff) * 16 + u];
        float f[8];
        unpack8(q, f);
        float nm = h2f((unsigned short)((unsigned)a.y >> 16));
#pragma unroll
        for (int k = 0; k < 8; ++k) acc0[k] = fmaf(nm, f[k], acc0[k]);
    }
    // drain row 1
    for (; j1 + 2 <= e1; j1 += 2) {
        int2 c0 = ew[j1], c1 = ew[j1 + 1];
        uint4 qc0 = tab4[(size_t)(c0.y & 0xffff) * 16 + u];
        uint4 qc1 = tab4[(size_t)(c1.y & 0xffff) * 16 + u];
        float fc0[8], fc1[8];
        unpack8(qc0, fc0); unpack8(qc1, fc1);
        float nc0 = h2f((unsigned short)((unsigned)c0.y >> 16));
        float nc1 = h2f((unsigned short)((unsigned)c1.y >> 16));
#pragma unroll
        for (int k = 0; k < 8; ++k) acc1[k] += fmaf(nc0, fc0[k], nc1 * fc1[k]);
    }
    if (j1 < e1) {
        int2 c = ew[j1];
        uint4 q = tab4[(size_t)(c.y & 0xffff) * 16 + u];
        float f[8];
        unpack8(q, f);
        float nm = h2f((unsigned short)((unsigned)c.y >> 16));
#pragma unroll
        for (int k = 0; k < 8; ++k) acc1[k] = fmaf(nm, f[k], acc1[k]);
    }

    const float4 b0 = ((const float4*)bias)[u * 2];
    const float4 b1 = ((const float4*)bias)[u * 2 + 1];
    {
        float r[8];
        r[0] = fmaxf(fmaf(di0, acc0[0], b0.x), 0.0f);
        r[1] = fmaxf(fmaf(di0, acc0[1], b0.y), 0.0f);
        r[2] = fmaxf(fmaf(di0, acc0[2], b0.z), 0.0f);
        r[3] = fmaxf(fmaf(di0, acc0[3], b0.w), 0.0f);
        r[4] = fmaxf(fmaf(di0, acc0[4], b1.x), 0.0f);
        r[5] = fmaxf(fmaf(di0, acc0[5], b1.y), 0.0f);
        r[6] = fmaxf(fmaf(di0, acc0[6], b1.z), 0.0f);
        r[7] = fmaxf(fmaf(di0, acc0[7], b1.w), 0.0f);
        uint4 o;
        o.x = (unsigned)f2bf(r[0]) | ((unsigned)f2bf(r[1]) << 16);
        o.y = (unsigned)f2bf(r[2]) | ((unsigned)f2bf(r[3]) << 16);
        o.z = (unsigned)f2bf(r[4]) | ((unsigned)f2bf(r[5]) << 16);
        o.w = (unsigned)f2bf(r[6]) | ((unsigned)f2bf(r[7]) << 16);
        ((uint4*)outb)[(size_t)i0 * 16 + u] = o;
    }
    if (has1) {
        float r[8];
        r[0] = fmaxf(fmaf(di1, acc1[0], b0.x), 0.0f);
        r[1] = fmaxf(fmaf(di1, acc1[1], b0.y), 0.0f);
        r[2] = fmaxf(fmaf(di1, acc1[2], b0.z), 0.0f);
        r[3] = fmaxf(fmaf(di1, acc1[3], b0.w), 0.0f);
        r[4] = fmaxf(fmaf(di1, acc1[4], b1.x), 0.0f);
        r[5] = fmaxf(fmaf(di1, acc1[5], b1.y), 0.0f);
        r[6] = fmaxf(fmaf(di1, acc1[6], b1.z), 0.0f);
        r[7] = fmaxf(fmaf(di1, acc1[7], b1.w), 0.0f);
        uint4 o;
        o.x = (unsigned)f2bf(r[0]) | ((unsigned)f2bf(r[1]) << 16);
        o.y = (unsigned)f2bf(r[2]) | ((unsigned)f2bf(r[3]) << 16);
        o.z = (unsigned)f2bf(r[4]) | ((unsigned)f2bf(r[5]) << 16);
        o.w = (unsigned)f2bf(r[6]) | ((unsigned)f2bf(r[7]) << 16);
        ((uint4*)outb)[(size_t)i1 * 16 + u] = o;
    }
}

// ---------------- layer-2 aggregation: dual-row, vs2 rows pre-scaled, fp32 output ----
__global__ void aggregate2(const unsigned short* __restrict__ vs, const int* __restrict__ rp,
                           const int2* __restrict__ ew, const float* __restrict__ dinv,
                           const float* __restrict__ bias, float* __restrict__ out,
                           int n, int half) {
    int t = blockIdx.x * blockDim.x + threadIdx.x;
    int g = t >> 4, u = t & 15;
    if (g >= half) return;
    const uint4* vs4 = (const uint4*)vs;
    const int i0 = g, i1 = g + half;
    const bool has1 = (i1 < n);
    float acc0[8], acc1[8];
    unpack8(vs4[(size_t)i0 * 16 + u], acc0);  // self term (already di-scaled)
    if (has1) unpack8(vs4[(size_t)i1 * 16 + u], acc1);
    int j0 = (i0 == 0) ? 0 : rp[i0 - 1];
    const int e0 = rp[i0];
    int j1 = has1 ? rp[i1 - 1] : 0;
    const int e1 = has1 ? rp[i1] : 0;

    while (j0 + 2 <= e0 && j1 + 2 <= e1) {
        int s00 = ew[j0].x, s01 = ew[j0 + 1].x, s10 = ew[j1].x, s11 = ew[j1 + 1].x;
        uint4 q00 = vs4[(size_t)s00 * 16 + u];
        uint4 q01 = vs4[(size_t)s01 * 16 + u];
        uint4 q10 = vs4[(size_t)s10 * 16 + u];
        uint4 q11 = vs4[(size_t)s11 * 16 + u];
        float f00[8], f01[8], f10[8], f11[8];
        unpack8(q00, f00); unpack8(q01, f01); unpack8(q10, f10); unpack8(q11, f11);
#pragma unroll
        for (int k = 0; k < 8; ++k) {
            acc0[k] += f00[k] + f01[k];
            acc1[k] += f10[k] + f11[k];
        }
        j0 += 2; j1 += 2;
    }
    for (; j0 + 2 <= e0; j0 += 2) {
        int s00 = ew[j0].x, s01 = ew[j0 + 1].x;
        uint4 q00 = vs4[(size_t)s00 * 16 + u];
        uint4 q01 = vs4[(size_t)s01 * 16 + u];
        float f00[8], f01[8];
        unpack8(q00, f00); unpack8(q01, f01);
#pragma unroll
        for (int k = 0; k < 8; ++k) acc0[k] += f00[k] + f01[k];
    }
    if (j0 < e0) {
        uint4 q = vs4[(size_t)ew[j0].x * 16 + u];
        float f[8];
        unpack8(q, f);
#pragma unroll
        for (int k = 0; k < 8; ++k) acc0[k] += f[k];
    }
    for (; j1 + 2 <= e1; j1 += 2) {
        int s10 = ew[j1].x, s11 = ew[j1 + 1].x;
        uint4 q10 = vs4[(size_t)s10 * 16 + u];
        uint4 q11 = vs4[(size_t)s11 * 16 + u];
        float f10[8], f11[8];
        unpack8(q10, f10); unpack8(q11, f11);
#pragma unroll
        for (int k = 0; k < 8; ++k) acc1[k] += f10[k] + f11[k];
    }
    if (j1 < e1) {
        uint4 q = vs4[(size_t)ew[j1].x * 16 + u];
        float f[8];
        unpack8(q, f);
#pragma unroll
        for (int k = 0; k < 8; ++k) acc1[k] += f[k];
    }

    const float4 b0 = ((const float4*)bias)[u * 2];
    const float4 b1 = ((const float4*)bias)[u * 2 + 1];
    {
        float di = dinv[i0];
        float4 r0, r1;
        r0.x = fmaxf(fmaf(di, acc0[0], b0.x), 0.0f);
        r0.y = fmaxf(fmaf(di, acc0[1], b0.y), 0.0f);
        r0.z = fmaxf(fmaf(di, acc0[2], b0.z), 0.0f);
        r0.w = fmaxf(fmaf(di, acc0[3], b0.w), 0.0f);
        r1.x = fmaxf(fmaf(di, acc0[4], b1.x), 0.0f);
        r1.y = fmaxf(fmaf(di, acc0[5], b1.y), 0.0f);
        r1.z = fmaxf(fmaf(di, acc0[6], b1.z), 0.0f);
        r1.w = fmaxf(fmaf(di, acc0[7], b1.w), 0.0f);
        ((float4*)out)[(size_t)i0 * 32 + u * 2] = r0;
        ((float4*)out)[(size_t)i0 * 32 + u * 2 + 1] = r1;
    }
    if (has1) {
        float di = dinv[i1];
        float4 r0, r1;
        r0.x = fmaxf(fmaf(di, acc1[0], b0.x), 0.0f);
        r0.y = fmaxf(fmaf(di, acc1[1], b0.y), 0.0f);
        r0.z = fmaxf(fmaf(di, acc1[2], b0.z), 0.0f);
        r0.w = fmaxf(fmaf(di, acc1[3], b0.w), 0.0f);
        r1.x = fmaxf(fmaf(di, acc1[4], b1.x), 0.0f);
        r1.y = fmaxf(fmaf(di, acc1[5], b1.y), 0.0f);
        r1.z = fmaxf(fmaf(di, acc1[6], b1.z), 0.0f);
        r1.w = fmaxf(fmaf(di, acc1[7], b1.w), 0.0f);
        ((float4*)out)[(size_t)i1 * 32 + u * 2] = r0;
        ((float4*)out)[(size_t)i1 * 32 + u * 2 + 1] = r1;
    }
}

extern "C" void kernel_launch(void* const* d_in, const int* in_sizes, int n_in,
                              void* d_out, int out_size, void* d_ws, size_t ws_size,
                              hipStream_t stream) {
    const int* x = (const int*)d_in[0];
    const int* edge_index = (const int*)d_in[1];
    const float* emb = (const float*)d_in[2];
    const float* W1 = (const float*)d_in[3];
    const float* b1 = (const float*)d_in[4];
    const float* W2 = (const float*)d_in[5];
    const float* b2 = (const float*)d_in[6];
    float* out = (float*)d_out;

    const int N = in_sizes[0];
    const int E = in_sizes[1] / 2;
    const int V = in_sizes[2] / NDIM;  // vocab rows
    const int* src = edge_index;
    const int* dst = edge_index + E;

    char* p = (char*)d_ws;
    auto alloc = [&](size_t bytes) {
        char* q = p;
        p += (bytes + 511) & ~(size_t)511;
        return q;
    };
    int* cnt = (int*)alloc((size_t)N * sizeof(int));
    int* rp = (int*)alloc((size_t)N * sizeof(int));
    float* dinv = (float*)alloc((size_t)N * sizeof(float));
    int* bsums = (int*)alloc(128 * sizeof(int));
    int2* ew = (int2*)alloc((size_t)E * sizeof(int2));
    unsigned short* WT1 = (unsigned short*)alloc(16384 * sizeof(unsigned short));
    unsigned short* WT2 = (unsigned short*)alloc(16384 * sizeof(unsigned short));
    unsigned short* embW1 = (unsigned short*)alloc((size_t)V * NDIM * sizeof(unsigned short));
    unsigned short* h1b = (unsigned short*)alloc((size_t)N * NDIM * sizeof(unsigned short));
    unsigned short* vs2 = (unsigned short*)alloc((size_t)N * NDIM * sizeof(unsigned short));
    (void)ws_size;

    const int NB = (N + SCAN_IPB - 1) / SCAN_IPB;  // 98 <= 128
    const int nblkA = (N + 255) / 256;
    const int half = (N + 1) / 2;
    const int gemmBlocks = (V + 63) / 64;
    const int fillBlocks = (E / 2 + 255) / 256;

    // CSR build + dinv (rp becomes inclusive scan after gemm1_fill's fill branch)
    hipMemsetAsync(cnt, 0, (size_t)N * sizeof(int), stream);
    degree_count<<<(E / 2 + 255) / 256, 256, 0, stream>>>(dst, cnt, E);
    scan_blocks<<<NB, SCAN_BLK, 0, stream>>>(cnt, rp, bsums, N);
    scan_partials<<<1, 128, 0, stream>>>(bsums, NB);
    add_offsets_dinv_wt<<<nblkA + 128, 256, 0, stream>>>(rp, bsums, cnt, dinv, N, nblkA,
                                                         W1, W2, WT1, WT2);

    // fused: layer-1 vocab GEMM overlapped with edge fill (independent work)
    gemm1_fill<<<gemmBlocks + fillBlocks, 256, 0, stream>>>(
        emb, WT1, embW1, V, gemmBlocks, src, dst, rp, x, dinv, ew, E, fillBlocks);

    const int agg_blocks = (int)(((size_t)half * 16 + 255) / 256);

    aggregate1<<<agg_blocks, 256, 0, stream>>>(embW1, x, rp, ew, dinv, b1, h1b, N, half);
    gemm_mfma_b<<<(N + 63) / 64, 256, 0, stream>>>(h1b, WT2, dinv, vs2, N);
    aggregate2<<<agg_blocks, 256, 0, stream>>>(vs2, rp, ew, dinv, b2, out, N, half);
}